// Round 6
// baseline (165.937 us; speedup 1.0000x reference)
//
#include <hip/hip_runtime.h>
#include <hip/hip_bf16.h>

#define BATCH 32768
#define NF    64              // fields (K and N of the GEMM)
#define NE    12              // embedding dim
#define MB    16              // batch rows per block
#define MROWS (MB*NE)         // 192 M-rows per block
#define LSTR  68              // LDS f32 row stride (64 + 4 pad, b128-aligned)
#define NBLK  (BATCH/MB)      // 2048

typedef __attribute__((ext_vector_type(8))) short short8;   // 8 bf16 = 4 VGPR
typedef __attribute__((ext_vector_type(4))) float float4v;

// d_ws layout: ShT bf16[64][64] @0 (8KB) | SlT bf16[64][64] @8KB | WT f32[12][64] @16KB
#define WS_SHT 0
#define WS_SLT 8192
#define WS_WT  16384

__device__ __forceinline__ short bfb(float v) {
    union { __hip_bfloat16 h; short s; } u;
    u.h = __float2bfloat16(v);
    return u.s;
}

// ---- prep: S = 0.5*<V[i,j],V[j,i]> (0 diag), split bf16 hi/lo, stored
// TRANSPOSED [n][k] for B-frag b128 loads; WT[e][j] = W[j*12+e].
__global__ void prep_kernel(const float* __restrict__ V, const float* __restrict__ W,
                            unsigned short* __restrict__ ShT,
                            unsigned short* __restrict__ SlT,
                            float* __restrict__ WT) {
    const int idx = blockIdx.x * 256 + threadIdx.x;
    if (idx < NF * NF) {
        const int i = idx >> 6, j = idx & 63;
        const float4v a = *(const float4v*)(V + (size_t)((i << 6) | j) * 4);
        const float4v b = *(const float4v*)(V + (size_t)((j << 6) | i) * 4);
        const float s = (i == j) ? 0.0f
                      : 0.5f * (a.x * b.x + a.y * b.y + a.z * b.z + a.w * b.w);
        const __hip_bfloat16 sh = __float2bfloat16(s);
        union { __hip_bfloat16 h; unsigned short u; } uh, ul;
        uh.h = sh; ul.h = __float2bfloat16(s - __bfloat162float(sh));
        ShT[(j << 6) | i] = uh.u;
        SlT[(j << 6) | i] = ul.u;
    }
    if (idx < NF * NE) {               // 768
        const int j = idx / NE, e = idx - j * NE;
        WT[e * 64 + j] = W[idx];
    }
}

// 192x64 C-tile = A(192x64 bf16-split) x S(64x64 bf16-split), K=2x32, 3
// products, fp32 acc.  Wave w owns m-subtiles 3w..3w+2; each subtile's acc
// (16 VGPR) is produced AND consumed inside its ms iteration, so peak VGPR
// stays ~140 (< the launch_bounds cap 170) -> no scratch spill.
__global__ __launch_bounds__(256, 3) void ffm_mfma(
    const float* __restrict__ x,
    const float* __restrict__ bvec,
    const unsigned short* __restrict__ ShT,
    const unsigned short* __restrict__ SlT,
    const float* __restrict__ WT,
    float* __restrict__ out)
{
    __shared__ float Xs[MROWS * LSTR];   // 51 KB, [(b,e)][i] fp32
    __shared__ float red[MROWS];

    const int tid  = threadIdx.x;
    const int w    = tid >> 6;
    const int lane = tid & 63;
    const int l15  = lane & 15;
    const int q    = lane >> 4;

    // ---- phase 1: issue all 12 global x loads (deep queue for HBM overlap)
    const float4v* xg = (const float4v*)(x + (size_t)blockIdx.x * MB * (NF * NE));
    float4v v[12];
    #pragma unroll
    for (int p = 0; p < 12; ++p) v[p] = xg[p * 256 + tid];

    // ---- resident S fragments: B[k=q*8+j][n=l15] -> 16B rows of S^T (L2-hot)
    short8 shf[4][2], slf[4][2];
    #pragma unroll
    for (int ns = 0; ns < 4; ++ns)
        #pragma unroll
        for (int kb = 0; kb < 2; ++kb) {
            const int off = ((ns << 4) + l15) * 64 + kb * 32 + q * 8;
            shf[ns][kb] = *(const short8*)(ShT + off);
            slf[ns][kb] = *(const short8*)(SlT + off);
        }

    // ---- phase 2: scatter x tile to LDS transposed [(b,e)][i]
    #pragma unroll
    for (int p = 0; p < 12; ++p) {
        const int fid = p * 256 + tid;        // 0..3071
        const int b   = fid / 192;
        const int c4  = fid - b * 192;
        const int d0  = c4 * 4;
        const int i0  = d0 / 12;
        const int e0  = d0 - i0 * 12;         // in {0,4,8}: 4 elems same i0
        float* dst = Xs + (b * NE + e0) * LSTR + i0;
        dst[0 * LSTR] = v[p].x; dst[1 * LSTR] = v[p].y;
        dst[2 * LSTR] = v[p].z; dst[3 * LSTR] = v[p].w;
    }
    __syncthreads();

    #pragma unroll
    for (int ms = 0; ms < 3; ++ms) {
        const int msg  = w * 3 + ms;           // global m-subtile 0..11
        const int mrow = (msg << 4) + l15;     // A row: m = lane&15

        // A fragment: f32 from LDS -> bf16 hi/lo split
        float av[16];
        #pragma unroll
        for (int kb = 0; kb < 2; ++kb) {
            const float4v t0 = *(const float4v*)(Xs + mrow * LSTR + kb * 32 + q * 8);
            const float4v t1 = *(const float4v*)(Xs + mrow * LSTR + kb * 32 + q * 8 + 4);
            av[kb*8+0]=t0.x; av[kb*8+1]=t0.y; av[kb*8+2]=t0.z; av[kb*8+3]=t0.w;
            av[kb*8+4]=t1.x; av[kb*8+5]=t1.y; av[kb*8+6]=t1.z; av[kb*8+7]=t1.w;
        }
        short8 ah[2], al[2];
        #pragma unroll
        for (int kb = 0; kb < 2; ++kb)
            #pragma unroll
            for (int j = 0; j < 8; ++j) {
                const float vv = av[kb * 8 + j];
                const __hip_bfloat16 h = __float2bfloat16(vv);
                ah[kb][j] = bfb(vv);
                al[kb][j] = bfb(vv - __bfloat162float(h));
            }

        float4v acc[4];
        #pragma unroll
        for (int ns = 0; ns < 4; ++ns) {
            float4v c = (float4v){0.f, 0.f, 0.f, 0.f};
            c = __builtin_amdgcn_mfma_f32_16x16x32_bf16(ah[0], shf[ns][0], c, 0, 0, 0);
            c = __builtin_amdgcn_mfma_f32_16x16x32_bf16(ah[1], shf[ns][1], c, 0, 0, 0);
            c = __builtin_amdgcn_mfma_f32_16x16x32_bf16(al[0], shf[ns][0], c, 0, 0, 0);
            c = __builtin_amdgcn_mfma_f32_16x16x32_bf16(al[1], shf[ns][1], c, 0, 0, 0);
            c = __builtin_amdgcn_mfma_f32_16x16x32_bf16(ah[0], slf[ns][0], c, 0, 0, 0);
            c = __builtin_amdgcn_mfma_f32_16x16x32_bf16(ah[1], slf[ns][1], c, 0, 0, 0);
            acc[ns] = c;
        }

        // fused per-ms epilogue: P[m] = sum_n A_f32[m][n]*(C[m][n] + WT[e][n])
        // C/D layout: col n = l15, row m = q*4+rg
        #pragma unroll
        for (int rg = 0; rg < 4; ++rg) {
            const int m = (msg << 4) + (q << 2) + rg;
            const int e = m % NE;
            float p = 0.0f;
            #pragma unroll
            for (int ns = 0; ns < 4; ++ns) {
                const int n = (ns << 4) + l15;
                p = fmaf(Xs[m * LSTR + n], acc[ns][rg] + WT[e * 64 + n], p);
            }
            p += __shfl_xor(p, 1);
            p += __shfl_xor(p, 2);
            p += __shfl_xor(p, 4);
            p += __shfl_xor(p, 8);
            if (l15 == 0) red[m] = p;
        }
    }
    __syncthreads();

    if (tid < MB) {
        float s = 0.0f;
        #pragma unroll
        for (int e = 0; e < NE; ++e) s += red[tid * NE + e];
        const float z = s + bvec[0];
        out[blockIdx.x * MB + tid] = 1.0f / (1.0f + __expf(-z));
    }
}

extern "C" void kernel_launch(void* const* d_in, const int* in_sizes, int n_in,
                              void* d_out, int out_size, void* d_ws, size_t ws_size,
                              hipStream_t stream) {
    const float* x  = (const float*)d_in[0];
    const float* W  = (const float*)d_in[1];  // [1,768]
    const float* bb = (const float*)d_in[2];  // [1]
    const float* V  = (const float*)d_in[3];  // [64,64,4]
    unsigned short* ShT = (unsigned short*)((char*)d_ws + WS_SHT);
    unsigned short* SlT = (unsigned short*)((char*)d_ws + WS_SLT);
    float*          WT  = (float*)((char*)d_ws + WS_WT);
    float* out = (float*)d_out;

    prep_kernel<<<dim3(16), dim3(256), 0, stream>>>(V, W, ShT, SlT, WT);
    ffm_mfma<<<dim3(NBLK), dim3(256), 0, stream>>>(x, bb, ShT, SlT, WT, out);
}

// Round 7
// 156.424 us; speedup vs baseline: 1.0608x; 1.0608x over previous
//
#include <hip/hip_runtime.h>
#include <hip/hip_bf16.h>

#define BATCH 32768
#define NF    64              // fields (K and N of the GEMM)
#define NE    12              // embedding dim
#define MB    16              // batch rows per tile
#define MROWS (MB*NE)         // 192 M-rows per tile
#define LSTR  68              // LDS f32 row stride (64 + 4 pad, b128-aligned)
#define NTILE (BATCH/MB)      // 2048
#define GRID  512
#define TPB   (NTILE/GRID)    // 4 tiles per block

typedef __attribute__((ext_vector_type(8))) short short8;   // 8 bf16 = 4 VGPR
typedef __attribute__((ext_vector_type(4))) float float4v;

// d_ws layout: ShT bf16[64][64] @0 (8KB) | SlT bf16[64][64] @8KB | WT f32[12][64] @16KB
#define WS_SHT 0
#define WS_SLT 8192
#define WS_WT  16384

__device__ __forceinline__ short bfb(float v) {
    union { __hip_bfloat16 h; short s; } u;
    u.h = __float2bfloat16(v);
    return u.s;
}

// ---- prep: S = 0.5*<V[i,j],V[j,i]> (0 diag), split bf16 hi/lo, stored
// TRANSPOSED [n][k] for B-frag b128 loads; WT[e][j] = W[j*12+e].
__global__ void prep_kernel(const float* __restrict__ V, const float* __restrict__ W,
                            unsigned short* __restrict__ ShT,
                            unsigned short* __restrict__ SlT,
                            float* __restrict__ WT) {
    const int idx = blockIdx.x * 256 + threadIdx.x;
    if (idx < NF * NF) {
        const int i = idx >> 6, j = idx & 63;
        const float4v a = *(const float4v*)(V + (size_t)((i << 6) | j) * 4);
        const float4v b = *(const float4v*)(V + (size_t)((j << 6) | i) * 4);
        const float s = (i == j) ? 0.0f
                      : 0.5f * (a.x * b.x + a.y * b.y + a.z * b.z + a.w * b.w);
        const __hip_bfloat16 sh = __float2bfloat16(s);
        union { __hip_bfloat16 h; unsigned short u; } uh, ul;
        uh.h = sh; ul.h = __float2bfloat16(s - __bfloat162float(sh));
        ShT[(j << 6) | i] = uh.u;
        SlT[(j << 6) | i] = ul.u;
    }
    if (idx < NF * NE) {               // 768
        const int j = idx / NE, e = idx - j * NE;
        WT[e * 64 + j] = W[idx];
    }
}

// Persistent-ish blocks: 4 tiles each.  Per tile, the NEXT tile's 12 float4
// x-loads are issued right after the scatter barrier and stay in flight for
// the whole compute phase (~2300 cyc > 900-cyc HBM latency) -> continuous
// HBM streaming instead of per-block load convoys.
__global__ __launch_bounds__(256, 2) void ffm_mfma(
    const float* __restrict__ x,
    const float* __restrict__ bvec,
    const unsigned short* __restrict__ ShT,
    const unsigned short* __restrict__ SlT,
    const float* __restrict__ WT,
    float* __restrict__ out)
{
    __shared__ float Xs[MROWS * LSTR];   // 51 KB, [(b,e)][i] fp32
    __shared__ float red[MROWS];

    const int tid  = threadIdx.x;
    const int w    = tid >> 6;
    const int lane = tid & 63;
    const int l15  = lane & 15;
    const int q    = lane >> 4;

    // ---- resident S fragments: B[k=q*8+j][n=l15] -> 16B rows of S^T (L2-hot)
    short8 shf[4][2], slf[4][2];
    #pragma unroll
    for (int ns = 0; ns < 4; ++ns)
        #pragma unroll
        for (int kb = 0; kb < 2; ++kb) {
            const int off = ((ns << 4) + l15) * 64 + kb * 32 + q * 8;
            shf[ns][kb] = *(const short8*)(ShT + off);
            slf[ns][kb] = *(const short8*)(SlT + off);
        }

    // ---- prefetch tile 0 into registers
    float4v v[12];
    {
        const float4v* xg = (const float4v*)(x + (size_t)blockIdx.x * MB * (NF * NE));
        #pragma unroll
        for (int p = 0; p < 12; ++p) v[p] = xg[p * 256 + tid];
    }

    for (int tt = 0; tt < TPB; ++tt) {
        const int tile = tt * GRID + blockIdx.x;

        // ---- scatter prefetched tile to LDS transposed [(b,e)][i]
        #pragma unroll
        for (int p = 0; p < 12; ++p) {
            const int fid = p * 256 + tid;        // 0..3071
            const int b   = fid / 192;
            const int c4  = fid - b * 192;
            const int d0  = c4 * 4;
            const int i0  = d0 / 12;
            const int e0  = d0 - i0 * 12;         // in {0,4,8}
            float* dst = Xs + (b * NE + e0) * LSTR + i0;
            dst[0 * LSTR] = v[p].x; dst[1 * LSTR] = v[p].y;
            dst[2 * LSTR] = v[p].z; dst[3 * LSTR] = v[p].w;
        }
        __syncthreads();   // B1: Xs ready

        // ---- issue next tile's loads NOW (in flight during compute)
        if (tt + 1 < TPB) {
            const int ntile = (tt + 1) * GRID + blockIdx.x;
            const float4v* xg = (const float4v*)(x + (size_t)ntile * MB * (NF * NE));
            #pragma unroll
            for (int p = 0; p < 12; ++p) v[p] = xg[p * 256 + tid];
        }

        // ---- compute: 3 m-subtiles per wave, fused epilogue each
        #pragma unroll
        for (int ms = 0; ms < 3; ++ms) {
            const int msg  = w * 3 + ms;           // global m-subtile 0..11
            const int mrow = (msg << 4) + l15;     // A row: m = lane&15

            short8 ah[2], al[2];
            #pragma unroll
            for (int kb = 0; kb < 2; ++kb) {
                const float4v t0 = *(const float4v*)(Xs + mrow * LSTR + kb * 32 + q * 8);
                const float4v t1 = *(const float4v*)(Xs + mrow * LSTR + kb * 32 + q * 8 + 4);
                const float a8[8] = {t0.x, t0.y, t0.z, t0.w, t1.x, t1.y, t1.z, t1.w};
                #pragma unroll
                for (int j = 0; j < 8; ++j) {
                    const float vv = a8[j];
                    const __hip_bfloat16 h = __float2bfloat16(vv);
                    ah[kb][j] = bfb(vv);
                    al[kb][j] = bfb(vv - __bfloat162float(h));
                }
            }

            float4v acc[4];
            #pragma unroll
            for (int ns = 0; ns < 4; ++ns) {
                float4v c = (float4v){0.f, 0.f, 0.f, 0.f};
                c = __builtin_amdgcn_mfma_f32_16x16x32_bf16(ah[0], shf[ns][0], c, 0, 0, 0);
                c = __builtin_amdgcn_mfma_f32_16x16x32_bf16(ah[1], shf[ns][1], c, 0, 0, 0);
                c = __builtin_amdgcn_mfma_f32_16x16x32_bf16(al[0], shf[ns][0], c, 0, 0, 0);
                c = __builtin_amdgcn_mfma_f32_16x16x32_bf16(al[1], shf[ns][1], c, 0, 0, 0);
                c = __builtin_amdgcn_mfma_f32_16x16x32_bf16(ah[0], slf[ns][0], c, 0, 0, 0);
                c = __builtin_amdgcn_mfma_f32_16x16x32_bf16(ah[1], slf[ns][1], c, 0, 0, 0);
                acc[ns] = c;
            }

            // fused epilogue: P[m] = sum_n A_f32[m][n]*(C[m][n] + WT[e][n])
            // C/D: col n = l15, row m = q*4+rg
            #pragma unroll
            for (int rg = 0; rg < 4; ++rg) {
                const int m = (msg << 4) + (q << 2) + rg;
                const int e = m % NE;
                float p = 0.0f;
                #pragma unroll
                for (int ns = 0; ns < 4; ++ns) {
                    const int n = (ns << 4) + l15;
                    p = fmaf(Xs[m * LSTR + n], acc[ns][rg] + WT[e * 64 + n], p);
                }
                p += __shfl_xor(p, 1);
                p += __shfl_xor(p, 2);
                p += __shfl_xor(p, 4);
                p += __shfl_xor(p, 8);
                if (l15 == 0) red[m] = p;
            }
        }
        __syncthreads();   // B2: red ready, Xs free for next scatter

        if (tid < MB) {
            float s = 0.0f;
            #pragma unroll
            for (int e = 0; e < NE; ++e) s += red[tid * NE + e];
            const float z = s + bvec[0];
            out[tile * MB + tid] = 1.0f / (1.0f + __expf(-z));
        }
    }
}

extern "C" void kernel_launch(void* const* d_in, const int* in_sizes, int n_in,
                              void* d_out, int out_size, void* d_ws, size_t ws_size,
                              hipStream_t stream) {
    const float* x  = (const float*)d_in[0];
    const float* W  = (const float*)d_in[1];  // [1,768]
    const float* bb = (const float*)d_in[2];  // [1]
    const float* V  = (const float*)d_in[3];  // [64,64,4]
    unsigned short* ShT = (unsigned short*)((char*)d_ws + WS_SHT);
    unsigned short* SlT = (unsigned short*)((char*)d_ws + WS_SLT);
    float*          WT  = (float*)((char*)d_ws + WS_WT);
    float* out = (float*)d_out;

    prep_kernel<<<dim3(16), dim3(256), 0, stream>>>(V, W, ShT, SlT, WT);
    ffm_mfma<<<dim3(GRID), dim3(256), 0, stream>>>(x, bb, ShT, SlT, WT, out);
}